// Round 1
// baseline (492.481 us; speedup 1.0000x reference)
//
#include <hip/hip_runtime.h>
#include <cstdint>

// Problem constants
#define C_IN   128
#define C_OUT  256
#define KK     1152      // C_IN * 9 (im2col K)
#define NPIX   4096      // 64*64
#define BS     16
#define M_ROWS 65536     // BS * NPIX
#define QMAXF  127.0f

typedef int v4i __attribute__((ext_vector_type(4)));

// ---- workspace layout (bytes) ----
// qA       : int8 [M_ROWS][KK]        @ 0          (75,497,472)
// qW       : int8 [C_OUT][KK]         @ 75497472   (294,912)
// scale    : f32 [KK]                 @ 75792384
// qmul     : f32 [KK]  (1/(scale*s_x))@ 75796992
// act_part : f32 [8][KK]              @ 75801600   (36,864)
// w_scale  : f32 [KK]                 @ 75838464
// scalars  : f32 [4] {s_x,s_w,s_x*s_w}@ 75843072
#define OFF_QW    75497472
#define OFF_SCALE 75792384
#define OFF_QMUL  75796992
#define OFF_APART 75801600
#define OFF_WSC   75838464
#define OFF_SCAL  75843072

// K1: per-channel, per-(kh,kw) region abs-max of x. Grid (128 ch, 8 slices of 2 batches).
// act_part[s][c*9 + kh*3 + kw] = max |x[b in slice, c, rows(kh), cols(kw)]|
__global__ void k_act_scale(const float* __restrict__ x, float* __restrict__ act_part) {
    const int c = blockIdx.x, s = blockIdx.y;
    const int tid = threadIdx.x;
    float m[9];
#pragma unroll
    for (int i = 0; i < 9; i++) m[i] = 0.f;
    // 2 batches per slice: 8192 pixels
    for (int p = tid; p < 2 * NPIX; p += 256) {
        int b = s * 2 + (p >> 12);
        int hw = p & 4095;
        int h = hw >> 6, w = hw & 63;
        float v = fabsf(x[b * (C_IN * NPIX) + c * NPIX + hw]);
        bool rr[3] = { h <= 62, true, h >= 1 };   // kh = 0,1,2 row ranges
        bool cc[3] = { w <= 62, true, w >= 1 };   // kw = 0,1,2 col ranges
#pragma unroll
        for (int i = 0; i < 3; i++)
#pragma unroll
            for (int jq = 0; jq < 3; jq++)
                m[i * 3 + jq] = fmaxf(m[i * 3 + jq], (rr[i] && cc[jq]) ? v : 0.f);
    }
    __shared__ float sm[9][4];
    int lane = tid & 63, wid = tid >> 6;
#pragma unroll
    for (int i = 0; i < 9; i++) {
        float v = m[i];
        for (int off = 32; off > 0; off >>= 1) v = fmaxf(v, __shfl_down(v, off));
        if (lane == 0) sm[i][wid] = v;
    }
    __syncthreads();
    if (tid < 9) {
        float v = fmaxf(fmaxf(sm[tid][0], sm[tid][1]), fmaxf(sm[tid][2], sm[tid][3]));
        act_part[s * KK + c * 9 + tid] = v;
    }
}

// K2: w_scale[j] = max_i |w[i*KK + j]|  (coalesced column-max)
__global__ void k_w_scale(const float* __restrict__ wgt, float* __restrict__ w_scale) {
    int j = blockIdx.x * 256 + threadIdx.x;
    if (j >= KK) return;
    float m = 0.f;
    for (int i = 0; i < C_OUT; i++) m = fmaxf(m, fabsf(wgt[i * KK + j]));
    w_scale[j] = m;
}

// K3: scale[j] = sqrt(act)/sqrt(w) (==0 -> 1); s_x = max_j(act/scale)/127; s_w = max_j(w*scale)/127;
//     qmul[j] = 1/(scale[j]*s_x). Single block, 1024 threads.
__global__ void k_scales(const float* __restrict__ act_part, const float* __restrict__ w_scale,
                         float* __restrict__ scale, float* __restrict__ qmul,
                         float* __restrict__ scalars) {
    const int tid = threadIdx.x;
    float sc_local[2] = {1.f, 1.f};
    float mx = 0.f, mw = 0.f;
#pragma unroll
    for (int t = 0; t < 2; t++) {
        int j = tid + t * 1024;
        if (j < KK) {
            float a = 0.f;
#pragma unroll
            for (int s = 0; s < 8; s++) a = fmaxf(a, act_part[s * KK + j]);
            float wv = w_scale[j];
            float sc = sqrtf(a) / sqrtf(wv);
            if (sc == 0.f) sc = 1.0f;
            scale[j] = sc;
            sc_local[t] = sc;
            mx = fmaxf(mx, a / sc);    // exact: max_r |cols[r,j]/sc| == fl(act/sc)
            mw = fmaxf(mw, wv * sc);   // exact: max_i |w2[i,j]*sc|  == fl(wsc*sc)
        }
    }
    __shared__ float smx[16], smw[16];
    __shared__ float s_x_sh;
    int lane = tid & 63, wid = tid >> 6;
    for (int off = 32; off > 0; off >>= 1) {
        mx = fmaxf(mx, __shfl_down(mx, off));
        mw = fmaxf(mw, __shfl_down(mw, off));
    }
    if (lane == 0) { smx[wid] = mx; smw[wid] = mw; }
    __syncthreads();
    if (tid == 0) {
        float a = 0.f, b = 0.f;
        for (int i = 0; i < 16; i++) { a = fmaxf(a, smx[i]); b = fmaxf(b, smw[i]); }
        float s_x = a / QMAXF; if (s_x == 0.f) s_x = 1.f;
        float s_w = b / QMAXF; if (s_w == 0.f) s_w = 1.f;
        scalars[0] = s_x; scalars[1] = s_w; scalars[2] = s_x * s_w;
        s_x_sh = s_x;
    }
    __syncthreads();
    float s_x = s_x_sh;
#pragma unroll
    for (int t = 0; t < 2; t++) {
        int j = tid + t * 1024;
        if (j < KK) qmul[j] = 1.0f / (sc_local[t] * s_x);
    }
}

// K4: quantize weights -> int8 [C_OUT][KK]. Exact divisions (tiny tensor).
__global__ void k_quant_w(const float* __restrict__ wgt, const float* __restrict__ scale,
                          const float* __restrict__ scalars, signed char* __restrict__ qW) {
    int idx = blockIdx.x * 256 + threadIdx.x;   // < 294912
    int j = idx % KK;
    float s_w = scalars[1];
    float t = wgt[idx] * scale[j];              // matches ref: fl(w2*scale)
    float q = rintf(t / s_w);                   // round-half-even, exact div
    q = fminf(fmaxf(q, -QMAXF), QMAXF);
    qW[idx] = (signed char)(int)q;
}

// K5: quantize im2col activations -> int8 qA[r][j], r=(b,oh,ow), j=(c,kh,kw).
// One char4 per thread; consecutive threads = consecutive j => coalesced writes.
__global__ void k_quant_x(const float* __restrict__ x, const float* __restrict__ qmul,
                          char4* __restrict__ qA4) {
    unsigned idx = blockIdx.x * 256 + threadIdx.x;       // < 65536*288, exact
    unsigned r = idx / 288u;
    unsigned jj = idx - r * 288u;
    int b = r >> 12, pix = r & 4095;
    int oh = pix >> 6, ow = pix & 63;
    const float* xb = x + b * (C_IN * NPIX) + pix;       // pixel base (h=oh,w=ow)
    int j0 = jj * 4;
    signed char res[4];
#pragma unroll
    for (int e = 0; e < 4; e++) {
        int j = j0 + e;
        int c = (unsigned)j / 9u;
        int rem = j - c * 9;
        int kh = (unsigned)rem / 3u;
        int dh = kh - 1;
        int dw = (rem - kh * 3) - 1;
        int h = oh + dh, w = ow + dw;
        float v = 0.f;
        if ((unsigned)h < 64u && (unsigned)w < 64u)
            v = xb[c * NPIX + dh * 64 + dw];
        float q = rintf(v * qmul[j]);
        q = fminf(fmaxf(q, -QMAXF), QMAXF);
        res[e] = (signed char)(int)q;
    }
    qA4[idx] = make_char4(res[0], res[1], res[2], res[3]);
}

// K6: int8 GEMM. D[c_out, r] = sum_k qW[c_out,k]*qA[r,k]; out = D*s_x*s_w + bias.
// A-operand = qW (M=256), B-operand = qA (N=65536). 128x128 block tile, BK=64,
// m97-style: global_load_lds width-16 staging, 16x16x64 i8 MFMA, 2x2 waves of 64x64.
__global__ __launch_bounds__(256) void k_gemm(const signed char* __restrict__ qW,
                                              const signed char* __restrict__ qA,
                                              const float* __restrict__ scalars,
                                              const float* __restrict__ bias,
                                              float* __restrict__ out) {
    __shared__ __align__(16) signed char As[128 * 64];  // qW tile [m][k]
    __shared__ __align__(16) signed char Bs[128 * 64];  // qA tile [n][k]
    const int tid = threadIdx.x;
    const int lane = tid & 63, wvid = tid >> 6;
    const int wm = wvid & 1, wn = wvid >> 1;            // 2x2 wave grid
    const int blockN = blockIdx.x;                      // 0..511 (pixel rows)
    const int blockM = blockIdx.y;                      // 0..1   (c_out)

    // staging source base: row = 16*chunk + lane/4, 16B chunk = lane%4
    const signed char* aG = qW + (size_t)(blockM * 128 + (lane >> 2)) * KK + (lane & 3) * 16;
    const signed char* bG = qA + ((size_t)blockN * 128 + (lane >> 2)) * KK + (lane & 3) * 16;

    v4i acc[4][4];
#pragma unroll
    for (int i = 0; i < 4; i++)
#pragma unroll
        for (int jq = 0; jq < 4; jq++) acc[i][jq] = (v4i){0, 0, 0, 0};

    for (int k0 = 0; k0 < KK; k0 += 64) {
#pragma unroll
        for (int cch = 0; cch < 2; cch++) {
            int ca = wvid * 2 + cch;  // 8 chunks of 16 rows each
            __builtin_amdgcn_global_load_lds(
                (const __attribute__((address_space(1))) void*)(aG + (size_t)(ca * 16) * KK + k0),
                (__attribute__((address_space(3))) void*)(As + ca * 1024), 16, 0, 0);
            __builtin_amdgcn_global_load_lds(
                (const __attribute__((address_space(1))) void*)(bG + (size_t)(ca * 16) * KK + k0),
                (__attribute__((address_space(3))) void*)(Bs + ca * 1024), 16, 0, 0);
        }
        __syncthreads();
        v4i af[4], bf[4];
#pragma unroll
        for (int t = 0; t < 4; t++) {
            af[t] = *(const v4i*)(As + (wm * 64 + t * 16 + (lane & 15)) * 64 + (lane >> 4) * 16);
            bf[t] = *(const v4i*)(Bs + (wn * 64 + t * 16 + (lane & 15)) * 64 + (lane >> 4) * 16);
        }
#pragma unroll
        for (int mt = 0; mt < 4; mt++)
#pragma unroll
            for (int nt = 0; nt < 4; nt++)
                acc[mt][nt] = __builtin_amdgcn_mfma_i32_16x16x64_i8(af[mt], bf[nt], acc[mt][nt], 0, 0, 0);
        __syncthreads();
    }

    const float ssp = scalars[2];  // s_x * s_w
    const int quad = lane >> 4, col = lane & 15;
    float bv[4][4];
#pragma unroll
    for (int mt = 0; mt < 4; mt++)
#pragma unroll
        for (int rg = 0; rg < 4; rg++)
            bv[mt][rg] = bias[blockM * 128 + wm * 64 + mt * 16 + quad * 4 + rg];

#pragma unroll
    for (int mt = 0; mt < 4; mt++) {
#pragma unroll
        for (int nt = 0; nt < 4; nt++) {
            int n_g = blockN * 128 + wn * 64 + nt * 16 + col;  // global pixel row
            int b = n_g >> 12, pix = n_g & 4095;
#pragma unroll
            for (int rg = 0; rg < 4; rg++) {
                int m_g = blockM * 128 + wm * 64 + mt * 16 + quad * 4 + rg;  // c_out
                float v = (float)acc[mt][nt][rg] * ssp + bv[mt][rg];
                out[(size_t)(b * C_OUT + m_g) * NPIX + pix] = v;
            }
        }
    }
}

extern "C" void kernel_launch(void* const* d_in, const int* in_sizes, int n_in,
                              void* d_out, int out_size, void* d_ws, size_t ws_size,
                              hipStream_t stream) {
    const float* x    = (const float*)d_in[0];  // [16,128,64,64]
    const float* wgt  = (const float*)d_in[1];  // [256,128,3,3]
    const float* bias = (const float*)d_in[2];  // [256]
    float* out = (float*)d_out;                 // [16,256,64,64] fp32

    char* ws = (char*)d_ws;
    signed char* qA      = (signed char*)ws;
    signed char* qW      = (signed char*)(ws + OFF_QW);
    float* scale         = (float*)(ws + OFF_SCALE);
    float* qmul          = (float*)(ws + OFF_QMUL);
    float* act_part      = (float*)(ws + OFF_APART);
    float* w_scale       = (float*)(ws + OFF_WSC);
    float* scalars       = (float*)(ws + OFF_SCAL);

    k_act_scale<<<dim3(C_IN, 8), 256, 0, stream>>>(x, act_part);
    k_w_scale<<<5, 256, 0, stream>>>(wgt, w_scale);
    k_scales<<<1, 1024, 0, stream>>>(act_part, w_scale, scale, qmul, scalars);
    k_quant_w<<<KK, 256, 0, stream>>>(wgt, scale, scalars, qW);
    k_quant_x<<<(M_ROWS * 288) / 256, 256, 0, stream>>>(x, qmul, (char4*)qA);
    k_gemm<<<dim3(M_ROWS / 128, C_OUT / 128), 256, 0, stream>>>(qW, qA, scalars, bias, out);
}

// Round 2
// 240.489 us; speedup vs baseline: 2.0478x; 2.0478x over previous
//
#include <hip/hip_runtime.h>
#include <cstdint>

// Problem constants
#define C_IN   128
#define C_OUT  256
#define KK     1152      // C_IN * 9 (im2col K)
#define NPIX   4096      // 64*64
#define BS     16
#define M_ROWS 65536     // BS * NPIX
#define QMAXF  127.0f

typedef int v4i __attribute__((ext_vector_type(4)));

// ---- workspace layout (bytes) ----
#define OFF_QW    75497472
#define OFF_SCALE 75792384
#define OFF_QMUL  75796992
#define OFF_APART 75801600
#define OFF_WSC   75838464
#define OFF_SCAL  75843072

// K1: per-channel, per-(kh,kw) region abs-max of x. Grid (128 ch, 8 slices of 2 batches).
__global__ void k_act_scale(const float* __restrict__ x, float* __restrict__ act_part) {
    const int c = blockIdx.x, s = blockIdx.y;
    const int tid = threadIdx.x;
    float m[9];
#pragma unroll
    for (int i = 0; i < 9; i++) m[i] = 0.f;
    for (int p = tid; p < 2 * NPIX; p += 256) {
        int b = s * 2 + (p >> 12);
        int hw = p & 4095;
        int h = hw >> 6, w = hw & 63;
        float v = fabsf(x[b * (C_IN * NPIX) + c * NPIX + hw]);
        bool rr[3] = { h <= 62, true, h >= 1 };
        bool cc[3] = { w <= 62, true, w >= 1 };
#pragma unroll
        for (int i = 0; i < 3; i++)
#pragma unroll
            for (int jq = 0; jq < 3; jq++)
                m[i * 3 + jq] = fmaxf(m[i * 3 + jq], (rr[i] && cc[jq]) ? v : 0.f);
    }
    __shared__ float sm[9][4];
    int lane = tid & 63, wid = tid >> 6;
#pragma unroll
    for (int i = 0; i < 9; i++) {
        float v = m[i];
        for (int off = 32; off > 0; off >>= 1) v = fmaxf(v, __shfl_down(v, off));
        if (lane == 0) sm[i][wid] = v;
    }
    __syncthreads();
    if (tid < 9) {
        float v = fmaxf(fmaxf(sm[tid][0], sm[tid][1]), fmaxf(sm[tid][2], sm[tid][3]));
        act_part[s * KK + c * 9 + tid] = v;
    }
}

// K2: w_scale[j] = max_i |w[i*KK + j]|
__global__ void k_w_scale(const float* __restrict__ wgt, float* __restrict__ w_scale) {
    int j = blockIdx.x * 256 + threadIdx.x;
    if (j >= KK) return;
    float m = 0.f;
    for (int i = 0; i < C_OUT; i++) m = fmaxf(m, fabsf(wgt[i * KK + j]));
    w_scale[j] = m;
}

// K3: scales + s_x + s_w + qmul. Single block, 1024 threads.
__global__ void k_scales(const float* __restrict__ act_part, const float* __restrict__ w_scale,
                         float* __restrict__ scale, float* __restrict__ qmul,
                         float* __restrict__ scalars) {
    const int tid = threadIdx.x;
    float sc_local[2] = {1.f, 1.f};
    float mx = 0.f, mw = 0.f;
#pragma unroll
    for (int t = 0; t < 2; t++) {
        int j = tid + t * 1024;
        if (j < KK) {
            float a = 0.f;
#pragma unroll
            for (int s = 0; s < 8; s++) a = fmaxf(a, act_part[s * KK + j]);
            float wv = w_scale[j];
            float sc = sqrtf(a) / sqrtf(wv);
            if (sc == 0.f) sc = 1.0f;
            scale[j] = sc;
            sc_local[t] = sc;
            mx = fmaxf(mx, a / sc);
            mw = fmaxf(mw, wv * sc);
        }
    }
    __shared__ float smx[16], smw[16];
    __shared__ float s_x_sh;
    int lane = tid & 63, wid = tid >> 6;
    for (int off = 32; off > 0; off >>= 1) {
        mx = fmaxf(mx, __shfl_down(mx, off));
        mw = fmaxf(mw, __shfl_down(mw, off));
    }
    if (lane == 0) { smx[wid] = mx; smw[wid] = mw; }
    __syncthreads();
    if (tid == 0) {
        float a = 0.f, b = 0.f;
        for (int i = 0; i < 16; i++) { a = fmaxf(a, smx[i]); b = fmaxf(b, smw[i]); }
        float s_x = a / QMAXF; if (s_x == 0.f) s_x = 1.f;
        float s_w = b / QMAXF; if (s_w == 0.f) s_w = 1.f;
        scalars[0] = s_x; scalars[1] = s_w; scalars[2] = s_x * s_w;
        s_x_sh = s_x;
    }
    __syncthreads();
    float s_x = s_x_sh;
#pragma unroll
    for (int t = 0; t < 2; t++) {
        int j = tid + t * 1024;
        if (j < KK) qmul[j] = 1.0f / (sc_local[t] * s_x);
    }
}

// K4: quantize weights -> int8 [C_OUT][KK].
__global__ void k_quant_w(const float* __restrict__ wgt, const float* __restrict__ scale,
                          const float* __restrict__ scalars, signed char* __restrict__ qW) {
    int idx = blockIdx.x * 256 + threadIdx.x;
    int j = idx % KK;
    float s_w = scalars[1];
    float t = wgt[idx] * scale[j];
    float q = rintf(t / s_w);
    q = fminf(fmaxf(q, -QMAXF), QMAXF);
    qW[idx] = (signed char)(int)q;
}

// K5 v2: quantized im2col, all-coalesced.
// Block = (channel-half, row-pair, batch). Wave handles one (channel, out-row):
// 3 coalesced x-row loads + shfl for w±1 taps -> 9 quantized bytes/pixel into an
// LDS-staged tile (row stride 580 B: dword stride 145 is odd -> lanes 0..31 hit
// distinct banks; lane+32 aliasing is the free 2-way). Then coalesced dword writeout.
#define QX_LDSROW 580
__global__ __launch_bounds__(256) void k_quant_x2(const float* __restrict__ x,
                                                  const float* __restrict__ qmul,
                                                  signed char* __restrict__ qA) {
    __shared__ float qm[576];                    // qmul slice [64 ch][9]
    __shared__ signed char ob[128 * QX_LDSROW];  // 128 px x 576(+4 pad) bytes
    const int tid = threadIdx.x;
    const int ch  = blockIdx.x;   // channel half 0..1
    const int rp  = blockIdx.y;   // row pair 0..31
    const int b   = blockIdx.z;   // batch 0..15
    const int c0  = ch * 64;
    const int oh0 = rp * 2;

    for (int i = tid; i < 576; i += 256) qm[i] = qmul[c0 * 9 + i];
    __syncthreads();

    const int lane = tid & 63, wv = tid >> 6;
    const float* xb = x + (size_t)b * (C_IN * NPIX);

    for (int it = 0; it < 32; it++) {
        int pair = wv + 4 * it;          // 0..127 = (local c, row-in-pair)
        int c = pair >> 1;
        int oh = oh0 + (pair & 1);
        const float* xp = xb + (c0 + c) * NPIX + oh * 64 + lane;
        float xm = (oh >= 1)  ? xp[-64] : 0.f;   // row oh-1
        float x0 = xp[0];                        // row oh
        float xq = (oh <= 62) ? xp[64]  : 0.f;   // row oh+1
        float xm_l = __shfl_up(xm, 1);  if (lane == 0)  xm_l = 0.f;
        float xm_r = __shfl_down(xm, 1); if (lane == 63) xm_r = 0.f;
        float x0_l = __shfl_up(x0, 1);  if (lane == 0)  x0_l = 0.f;
        float x0_r = __shfl_down(x0, 1); if (lane == 63) x0_r = 0.f;
        float xq_l = __shfl_up(xq, 1);  if (lane == 0)  xq_l = 0.f;
        float xq_r = __shfl_down(xq, 1); if (lane == 63) xq_r = 0.f;
        float win[9] = { xm_l, xm, xm_r, x0_l, x0, x0_r, xq_l, xq, xq_r };
        signed char* orow = ob + ((oh - oh0) * 64 + lane) * QX_LDSROW + c * 9;
#pragma unroll
        for (int t = 0; t < 9; t++) {
            float q = rintf(win[t] * qm[c * 9 + t]);
            q = fminf(fmaxf(q, -QMAXF), QMAXF);
            orow[t] = (signed char)(int)q;
        }
    }
    __syncthreads();

    // writeout: 128 rows x 576 B, dword-granular, coalesced
    const int r0 = b * NPIX + oh0 * 64;
    for (int idx = tid; idx < 128 * 144; idx += 256) {
        int px = (unsigned)idx / 144u;
        int q  = idx - px * 144;
        int v  = *(const int*)(ob + px * QX_LDSROW + q * 4);
        *(int*)(qA + (size_t)(r0 + px) * KK + c0 * 9 + q * 4) = v;
    }
}

// K6: int8 GEMM (unchanged from R0). 128x128 tile, BK=64, global_load_lds staging.
__global__ __launch_bounds__(256) void k_gemm(const signed char* __restrict__ qW,
                                              const signed char* __restrict__ qA,
                                              const float* __restrict__ scalars,
                                              const float* __restrict__ bias,
                                              float* __restrict__ out) {
    __shared__ __align__(16) signed char As[128 * 64];
    __shared__ __align__(16) signed char Bs[128 * 64];
    const int tid = threadIdx.x;
    const int lane = tid & 63, wvid = tid >> 6;
    const int wm = wvid & 1, wn = wvid >> 1;
    const int blockN = blockIdx.x;
    const int blockM = blockIdx.y;

    const signed char* aG = qW + (size_t)(blockM * 128 + (lane >> 2)) * KK + (lane & 3) * 16;
    const signed char* bG = qA + ((size_t)blockN * 128 + (lane >> 2)) * KK + (lane & 3) * 16;

    v4i acc[4][4];
#pragma unroll
    for (int i = 0; i < 4; i++)
#pragma unroll
        for (int jq = 0; jq < 4; jq++) acc[i][jq] = (v4i){0, 0, 0, 0};

    for (int k0 = 0; k0 < KK; k0 += 64) {
#pragma unroll
        for (int cch = 0; cch < 2; cch++) {
            int ca = wvid * 2 + cch;
            __builtin_amdgcn_global_load_lds(
                (const __attribute__((address_space(1))) void*)(aG + (size_t)(ca * 16) * KK + k0),
                (__attribute__((address_space(3))) void*)(As + ca * 1024), 16, 0, 0);
            __builtin_amdgcn_global_load_lds(
                (const __attribute__((address_space(1))) void*)(bG + (size_t)(ca * 16) * KK + k0),
                (__attribute__((address_space(3))) void*)(Bs + ca * 1024), 16, 0, 0);
        }
        __syncthreads();
        v4i af[4], bf[4];
#pragma unroll
        for (int t = 0; t < 4; t++) {
            af[t] = *(const v4i*)(As + (wm * 64 + t * 16 + (lane & 15)) * 64 + (lane >> 4) * 16);
            bf[t] = *(const v4i*)(Bs + (wn * 64 + t * 16 + (lane & 15)) * 64 + (lane >> 4) * 16);
        }
#pragma unroll
        for (int mt = 0; mt < 4; mt++)
#pragma unroll
            for (int nt = 0; nt < 4; nt++)
                acc[mt][nt] = __builtin_amdgcn_mfma_i32_16x16x64_i8(af[mt], bf[nt], acc[mt][nt], 0, 0, 0);
        __syncthreads();
    }

    const float ssp = scalars[2];
    const int quad = lane >> 4, col = lane & 15;
    float bv[4][4];
#pragma unroll
    for (int mt = 0; mt < 4; mt++)
#pragma unroll
        for (int rg = 0; rg < 4; rg++)
            bv[mt][rg] = bias[blockM * 128 + wm * 64 + mt * 16 + quad * 4 + rg];

#pragma unroll
    for (int mt = 0; mt < 4; mt++) {
#pragma unroll
        for (int nt = 0; nt < 4; nt++) {
            int n_g = blockN * 128 + wn * 64 + nt * 16 + col;
            int b = n_g >> 12, pix = n_g & 4095;
#pragma unroll
            for (int rg = 0; rg < 4; rg++) {
                int m_g = blockM * 128 + wm * 64 + mt * 16 + quad * 4 + rg;
                float v = (float)acc[mt][nt][rg] * ssp + bv[mt][rg];
                out[(size_t)(b * C_OUT + m_g) * NPIX + pix] = v;
            }
        }
    }
}

extern "C" void kernel_launch(void* const* d_in, const int* in_sizes, int n_in,
                              void* d_out, int out_size, void* d_ws, size_t ws_size,
                              hipStream_t stream) {
    const float* x    = (const float*)d_in[0];
    const float* wgt  = (const float*)d_in[1];
    const float* bias = (const float*)d_in[2];
    float* out = (float*)d_out;

    char* ws = (char*)d_ws;
    signed char* qA = (signed char*)ws;
    signed char* qW = (signed char*)(ws + OFF_QW);
    float* scale    = (float*)(ws + OFF_SCALE);
    float* qmul     = (float*)(ws + OFF_QMUL);
    float* act_part = (float*)(ws + OFF_APART);
    float* w_scale  = (float*)(ws + OFF_WSC);
    float* scalars  = (float*)(ws + OFF_SCAL);

    k_act_scale<<<dim3(C_IN, 8), 256, 0, stream>>>(x, act_part);
    k_w_scale<<<5, 256, 0, stream>>>(wgt, w_scale);
    k_scales<<<1, 1024, 0, stream>>>(act_part, w_scale, scale, qmul, scalars);
    k_quant_w<<<KK, 256, 0, stream>>>(wgt, scale, scalars, qW);
    k_quant_x2<<<dim3(2, 32, BS), 256, 0, stream>>>(x, qmul, qA);
    k_gemm<<<dim3(M_ROWS / 128, C_OUT / 128), 256, 0, stream>>>(qW, qA, scalars, bias, out);
}

// Round 3
// 185.952 us; speedup vs baseline: 2.6484x; 1.2933x over previous
//
#include <hip/hip_runtime.h>
#include <cstdint>

// Problem constants
#define C_IN   128
#define C_OUT  256
#define KK     1152      // C_IN * 9 (im2col K)
#define NPIX   4096      // 64*64
#define BS     16
#define M_ROWS 65536     // BS * NPIX
#define QMAXF  127.0f

typedef int v4i __attribute__((ext_vector_type(4)));

// ---- workspace layout (bytes) ----
// qA       : int8 [M_ROWS][KK]        @ 0
// qW       : int8 [C_OUT][KK]         @ OFF_QW   (w_part f32[16][KK] aliases this
//                                                 region: consumed by k_scales
//                                                 BEFORE k_quant_w overwrites)
#define OFF_QW    75497472
#define OFF_SCALE 75792384
#define OFF_QMUL  75796992
#define OFF_APART 75801600
#define OFF_WSC   75838464   // (unused now, kept for layout stability)
#define OFF_SCAL  75843072

// K1: per-channel, per-(kh,kw) region abs-max of x. Grid (128 ch, 8 slices of 2 batches).
__global__ void k_act_scale(const float* __restrict__ x, float* __restrict__ act_part) {
    const int c = blockIdx.x, s = blockIdx.y;
    const int tid = threadIdx.x;
    float m[9];
#pragma unroll
    for (int i = 0; i < 9; i++) m[i] = 0.f;
    for (int p = tid; p < 2 * NPIX; p += 256) {
        int b = s * 2 + (p >> 12);
        int hw = p & 4095;
        int h = hw >> 6, w = hw & 63;
        float v = fabsf(x[b * (C_IN * NPIX) + c * NPIX + hw]);
        bool rr[3] = { h <= 62, true, h >= 1 };
        bool cc[3] = { w <= 62, true, w >= 1 };
#pragma unroll
        for (int i = 0; i < 3; i++)
#pragma unroll
            for (int jq = 0; jq < 3; jq++)
                m[i * 3 + jq] = fmaxf(m[i * 3 + jq], (rr[i] && cc[jq]) ? v : 0.f);
    }
    __shared__ float sm[9][4];
    int lane = tid & 63, wid = tid >> 6;
#pragma unroll
    for (int i = 0; i < 9; i++) {
        float v = m[i];
        for (int off = 32; off > 0; off >>= 1) v = fmaxf(v, __shfl_down(v, off));
        if (lane == 0) sm[i][wid] = v;
    }
    __syncthreads();
    if (tid < 9) {
        float v = fmaxf(fmaxf(sm[tid][0], sm[tid][1]), fmaxf(sm[tid][2], sm[tid][3]));
        act_part[s * KK + c * 9 + tid] = v;
    }
}

// K2 v2: two-stage column max. Grid (5, 16): j = bx*256+tid, 16 row-slices of 16.
// Coalesced across j; 16 independent loads in flight per thread.
__global__ void k_w_scale(const float* __restrict__ wgt, float* __restrict__ w_part) {
    int j = blockIdx.x * 256 + threadIdx.x;
    int s = blockIdx.y;
    if (j >= KK) return;
    const float* p = wgt + (size_t)s * 16 * KK + j;
    float m = 0.f;
#pragma unroll
    for (int i = 0; i < 16; i++) m = fmaxf(m, fabsf(p[(size_t)i * KK]));
    w_part[s * KK + j] = m;
}

// K3: scales + s_x + s_w + qmul. Single block, 1024 threads.
__global__ void k_scales(const float* __restrict__ act_part, const float* __restrict__ w_part,
                         float* __restrict__ scale, float* __restrict__ qmul,
                         float* __restrict__ scalars) {
    const int tid = threadIdx.x;
    float sc_local[2] = {1.f, 1.f};
    float mx = 0.f, mw = 0.f;
#pragma unroll
    for (int t = 0; t < 2; t++) {
        int j = tid + t * 1024;
        if (j < KK) {
            float a = 0.f;
#pragma unroll
            for (int s = 0; s < 8; s++) a = fmaxf(a, act_part[s * KK + j]);
            float wv = 0.f;
#pragma unroll
            for (int s = 0; s < 16; s++) wv = fmaxf(wv, w_part[s * KK + j]);
            float sc = sqrtf(a) / sqrtf(wv);
            if (sc == 0.f) sc = 1.0f;
            scale[j] = sc;
            sc_local[t] = sc;
            mx = fmaxf(mx, a / sc);    // exact: max_r |cols[r,j]/sc| == fl(act/sc)
            mw = fmaxf(mw, wv * sc);   // exact: max_i |w2[i,j]*sc|  == fl(wsc*sc)
        }
    }
    __shared__ float smx[16], smw[16];
    __shared__ float s_x_sh;
    int lane = tid & 63, wid = tid >> 6;
    for (int off = 32; off > 0; off >>= 1) {
        mx = fmaxf(mx, __shfl_down(mx, off));
        mw = fmaxf(mw, __shfl_down(mw, off));
    }
    if (lane == 0) { smx[wid] = mx; smw[wid] = mw; }
    __syncthreads();
    if (tid == 0) {
        float a = 0.f, b = 0.f;
        for (int i = 0; i < 16; i++) { a = fmaxf(a, smx[i]); b = fmaxf(b, smw[i]); }
        float s_x = a / QMAXF; if (s_x == 0.f) s_x = 1.f;
        float s_w = b / QMAXF; if (s_w == 0.f) s_w = 1.f;
        scalars[0] = s_x; scalars[1] = s_w; scalars[2] = s_x * s_w;
        s_x_sh = s_x;
    }
    __syncthreads();
    float s_x = s_x_sh;
#pragma unroll
    for (int t = 0; t < 2; t++) {
        int j = tid + t * 1024;
        if (j < KK) qmul[j] = 1.0f / (sc_local[t] * s_x);
    }
}

// K4: quantize weights -> int8 [C_OUT][KK].
__global__ void k_quant_w(const float* __restrict__ wgt, const float* __restrict__ scale,
                          const float* __restrict__ scalars, signed char* __restrict__ qW) {
    int idx = blockIdx.x * 256 + threadIdx.x;
    int j = idx % KK;
    float s_w = scalars[1];
    float t = wgt[idx] * scale[j];
    float q = rintf(t / s_w);
    q = fminf(fmaxf(q, -QMAXF), QMAXF);
    qW[idx] = (signed char)(int)q;
}

// K5 v3: quantized im2col. Block = (channel-quarter, row-pair, batch); 2048 blocks,
// LDS 38.5 KB -> 4 blocks/CU. Wave handles one (channel, out-row): 3 coalesced row
// loads + shfl halos -> 9 quantized bytes/pixel into LDS tile (row stride 292 B:
// dword stride 73, coprime with 32 banks -> conflict-free), then coalesced writeout.
#define QX_LDSROW 292
__global__ __launch_bounds__(256) void k_quant_x3(const float* __restrict__ x,
                                                  const float* __restrict__ qmul,
                                                  signed char* __restrict__ qA) {
    __shared__ float qm[288];                    // qmul slice [32 ch][9]
    __shared__ signed char ob[128 * QX_LDSROW];  // 128 px x 288(+4 pad) bytes
    const int tid = threadIdx.x;
    const int qt  = blockIdx.x;   // channel quarter 0..3
    const int rp  = blockIdx.y;   // row pair 0..31
    const int b   = blockIdx.z;   // batch 0..15
    const int c0  = qt * 32;
    const int oh0 = rp * 2;

    for (int i = tid; i < 288; i += 256) qm[i] = qmul[c0 * 9 + i];
    __syncthreads();

    const int lane = tid & 63, wv = tid >> 6;
    const float* xb = x + (size_t)b * (C_IN * NPIX);

    for (int it = 0; it < 16; it++) {
        int pair = wv + 4 * it;          // 0..63 = (local c, row-in-pair)
        int c = pair >> 1;
        int oh = oh0 + (pair & 1);
        const float* xp = xb + (c0 + c) * NPIX + oh * 64 + lane;
        float xm = (oh >= 1)  ? xp[-64] : 0.f;   // row oh-1
        float x0 = xp[0];                        // row oh
        float xq = (oh <= 62) ? xp[64]  : 0.f;   // row oh+1
        float xm_l = __shfl_up(xm, 1);  if (lane == 0)  xm_l = 0.f;
        float xm_r = __shfl_down(xm, 1); if (lane == 63) xm_r = 0.f;
        float x0_l = __shfl_up(x0, 1);  if (lane == 0)  x0_l = 0.f;
        float x0_r = __shfl_down(x0, 1); if (lane == 63) x0_r = 0.f;
        float xq_l = __shfl_up(xq, 1);  if (lane == 0)  xq_l = 0.f;
        float xq_r = __shfl_down(xq, 1); if (lane == 63) xq_r = 0.f;
        float win[9] = { xm_l, xm, xm_r, x0_l, x0, x0_r, xq_l, xq, xq_r };
        signed char* orow = ob + ((oh - oh0) * 64 + lane) * QX_LDSROW + c * 9;
#pragma unroll
        for (int t = 0; t < 9; t++) {
            float q = rintf(win[t] * qm[c * 9 + t]);
            q = fminf(fmaxf(q, -QMAXF), QMAXF);
            orow[t] = (signed char)(int)q;
        }
    }
    __syncthreads();

    // writeout: 128 rows x 288 B, dword-granular, coalesced 288-B runs
    const int r0 = b * NPIX + oh0 * 64;
    for (int idx = tid; idx < 128 * 72; idx += 256) {
        int px = (unsigned)idx / 72u;
        int q  = idx - px * 72;
        int v  = *(const int*)(ob + px * QX_LDSROW + q * 4);
        *(int*)(qA + (size_t)(r0 + px) * KK + c0 * 9 + q * 4) = v;
    }
}

// K6: int8 GEMM (unchanged). 128x128 tile, BK=64, global_load_lds staging.
__global__ __launch_bounds__(256) void k_gemm(const signed char* __restrict__ qW,
                                              const signed char* __restrict__ qA,
                                              const float* __restrict__ scalars,
                                              const float* __restrict__ bias,
                                              float* __restrict__ out) {
    __shared__ __align__(16) signed char As[128 * 64];
    __shared__ __align__(16) signed char Bs[128 * 64];
    const int tid = threadIdx.x;
    const int lane = tid & 63, wvid = tid >> 6;
    const int wm = wvid & 1, wn = wvid >> 1;
    const int blockN = blockIdx.x;
    const int blockM = blockIdx.y;

    const signed char* aG = qW + (size_t)(blockM * 128 + (lane >> 2)) * KK + (lane & 3) * 16;
    const signed char* bG = qA + ((size_t)blockN * 128 + (lane >> 2)) * KK + (lane & 3) * 16;

    v4i acc[4][4];
#pragma unroll
    for (int i = 0; i < 4; i++)
#pragma unroll
        for (int jq = 0; jq < 4; jq++) acc[i][jq] = (v4i){0, 0, 0, 0};

    for (int k0 = 0; k0 < KK; k0 += 64) {
#pragma unroll
        for (int cch = 0; cch < 2; cch++) {
            int ca = wvid * 2 + cch;
            __builtin_amdgcn_global_load_lds(
                (const __attribute__((address_space(1))) void*)(aG + (size_t)(ca * 16) * KK + k0),
                (__attribute__((address_space(3))) void*)(As + ca * 1024), 16, 0, 0);
            __builtin_amdgcn_global_load_lds(
                (const __attribute__((address_space(1))) void*)(bG + (size_t)(ca * 16) * KK + k0),
                (__attribute__((address_space(3))) void*)(Bs + ca * 1024), 16, 0, 0);
        }
        __syncthreads();
        v4i af[4], bf[4];
#pragma unroll
        for (int t = 0; t < 4; t++) {
            af[t] = *(const v4i*)(As + (wm * 64 + t * 16 + (lane & 15)) * 64 + (lane >> 4) * 16);
            bf[t] = *(const v4i*)(Bs + (wn * 64 + t * 16 + (lane & 15)) * 64 + (lane >> 4) * 16);
        }
#pragma unroll
        for (int mt = 0; mt < 4; mt++)
#pragma unroll
            for (int nt = 0; nt < 4; nt++)
                acc[mt][nt] = __builtin_amdgcn_mfma_i32_16x16x64_i8(af[mt], bf[nt], acc[mt][nt], 0, 0, 0);
        __syncthreads();
    }

    const float ssp = scalars[2];
    const int quad = lane >> 4, col = lane & 15;
    float bv[4][4];
#pragma unroll
    for (int mt = 0; mt < 4; mt++)
#pragma unroll
        for (int rg = 0; rg < 4; rg++)
            bv[mt][rg] = bias[blockM * 128 + wm * 64 + mt * 16 + quad * 4 + rg];

#pragma unroll
    for (int mt = 0; mt < 4; mt++) {
#pragma unroll
        for (int nt = 0; nt < 4; nt++) {
            int n_g = blockN * 128 + wn * 64 + nt * 16 + col;
            int b = n_g >> 12, pix = n_g & 4095;
#pragma unroll
            for (int rg = 0; rg < 4; rg++) {
                int m_g = blockM * 128 + wm * 64 + mt * 16 + quad * 4 + rg;
                float v = (float)acc[mt][nt][rg] * ssp + bv[mt][rg];
                out[(size_t)(b * C_OUT + m_g) * NPIX + pix] = v;
            }
        }
    }
}

extern "C" void kernel_launch(void* const* d_in, const int* in_sizes, int n_in,
                              void* d_out, int out_size, void* d_ws, size_t ws_size,
                              hipStream_t stream) {
    const float* x    = (const float*)d_in[0];
    const float* wgt  = (const float*)d_in[1];
    const float* bias = (const float*)d_in[2];
    float* out = (float*)d_out;

    char* ws = (char*)d_ws;
    signed char* qA = (signed char*)ws;
    signed char* qW = (signed char*)(ws + OFF_QW);
    float* w_part   = (float*)(ws + OFF_QW);      // aliases qW region (read before qW write)
    float* scale    = (float*)(ws + OFF_SCALE);
    float* qmul     = (float*)(ws + OFF_QMUL);
    float* act_part = (float*)(ws + OFF_APART);
    float* scalars  = (float*)(ws + OFF_SCAL);

    k_act_scale<<<dim3(C_IN, 8), 256, 0, stream>>>(x, act_part);
    k_w_scale<<<dim3(5, 16), 256, 0, stream>>>(wgt, w_part);
    k_scales<<<1, 1024, 0, stream>>>(act_part, w_part, scale, qmul, scalars);
    k_quant_w<<<KK, 256, 0, stream>>>(wgt, scale, scalars, qW);
    k_quant_x3<<<dim3(4, 32, BS), 256, 0, stream>>>(x, qmul, qA);
    k_gemm<<<dim3(M_ROWS / 128, C_OUT / 128), 256, 0, stream>>>(qW, qA, scalars, bias, out);
}

// Round 4
// 173.106 us; speedup vs baseline: 2.8450x; 1.0742x over previous
//
#include <hip/hip_runtime.h>
#include <cstdint>

// Problem constants
#define C_IN   128
#define C_OUT  256
#define KK     1152      // C_IN * 9 (im2col K)
#define NPIX   4096      // 64*64
#define BS     16
#define M_ROWS 65536     // BS * NPIX
#define QMAXF  127.0f

typedef int v4i __attribute__((ext_vector_type(4)));

// ---- workspace layout (bytes) ----
#define OFF_QW    75497472
#define OFF_SCALE 75792384
#define OFF_QMUL  75796992
#define OFF_APART 75801600
#define OFF_SCAL  75843072

// K-A: fused act_scale (blocks 0..1023) + w_scale (blocks 1024..1103).
__global__ void k_prep(const float* __restrict__ x, const float* __restrict__ wgt,
                       float* __restrict__ act_part, float* __restrict__ w_part) {
    const int tid = threadIdx.x;
    if (blockIdx.x >= 1024) {
        // w_scale: two-stage column max, coalesced across j
        int t = blockIdx.x - 1024;        // 0..79
        int j = (t % 5) * 256 + tid;
        int s = t / 5;                    // 0..15
        if (j >= KK) return;
        const float* p = wgt + (size_t)s * 16 * KK + j;
        float m = 0.f;
#pragma unroll
        for (int i = 0; i < 16; i++) m = fmaxf(m, fabsf(p[(size_t)i * KK]));
        w_part[s * KK + j] = m;
        return;
    }
    // act_scale: per-channel, per-(kh,kw) region abs-max
    const int c = blockIdx.x >> 3, s = blockIdx.x & 7;
    float m[9];
#pragma unroll
    for (int i = 0; i < 9; i++) m[i] = 0.f;
    for (int p = tid; p < 2 * NPIX; p += 256) {
        int b = s * 2 + (p >> 12);
        int hw = p & 4095;
        int h = hw >> 6, w = hw & 63;
        float v = fabsf(x[b * (C_IN * NPIX) + c * NPIX + hw]);
        bool rr[3] = { h <= 62, true, h >= 1 };
        bool cc[3] = { w <= 62, true, w >= 1 };
#pragma unroll
        for (int i = 0; i < 3; i++)
#pragma unroll
            for (int jq = 0; jq < 3; jq++)
                m[i * 3 + jq] = fmaxf(m[i * 3 + jq], (rr[i] && cc[jq]) ? v : 0.f);
    }
    __shared__ float sm[9][4];
    int lane = tid & 63, wid = tid >> 6;
#pragma unroll
    for (int i = 0; i < 9; i++) {
        float v = m[i];
        for (int off = 32; off > 0; off >>= 1) v = fmaxf(v, __shfl_down(v, off));
        if (lane == 0) sm[i][wid] = v;
    }
    __syncthreads();
    if (tid < 9) {
        float v = fmaxf(fmaxf(sm[tid][0], sm[tid][1]), fmaxf(sm[tid][2], sm[tid][3]));
        act_part[s * KK + c * 9 + tid] = v;
    }
}

// K-B: scales + s_x + s_w + qmul. Single block, 1024 threads.
__global__ void k_scales(const float* __restrict__ act_part, const float* __restrict__ w_part,
                         float* __restrict__ scale, float* __restrict__ qmul,
                         float* __restrict__ scalars) {
    const int tid = threadIdx.x;
    float sc_local[2] = {1.f, 1.f};
    float mx = 0.f, mw = 0.f;
#pragma unroll
    for (int t = 0; t < 2; t++) {
        int j = tid + t * 1024;
        if (j < KK) {
            float a = 0.f;
#pragma unroll
            for (int s = 0; s < 8; s++) a = fmaxf(a, act_part[s * KK + j]);
            float wv = 0.f;
#pragma unroll
            for (int s = 0; s < 16; s++) wv = fmaxf(wv, w_part[s * KK + j]);
            float sc = sqrtf(a) / sqrtf(wv);
            if (sc == 0.f) sc = 1.0f;
            scale[j] = sc;
            sc_local[t] = sc;
            mx = fmaxf(mx, a / sc);    // exact: max_r |cols[r,j]/sc| == fl(act/sc)
            mw = fmaxf(mw, wv * sc);   // exact: max_i |w2[i,j]*sc|  == fl(wsc*sc)
        }
    }
    __shared__ float smx[16], smw[16];
    __shared__ float s_x_sh;
    int lane = tid & 63, wid = tid >> 6;
    for (int off = 32; off > 0; off >>= 1) {
        mx = fmaxf(mx, __shfl_down(mx, off));
        mw = fmaxf(mw, __shfl_down(mw, off));
    }
    if (lane == 0) { smx[wid] = mx; smw[wid] = mw; }
    __syncthreads();
    if (tid == 0) {
        float a = 0.f, b = 0.f;
        for (int i = 0; i < 16; i++) { a = fmaxf(a, smx[i]); b = fmaxf(b, smw[i]); }
        float s_x = a / QMAXF; if (s_x == 0.f) s_x = 1.f;
        float s_w = b / QMAXF; if (s_w == 0.f) s_w = 1.f;
        scalars[0] = s_x; scalars[1] = s_w; scalars[2] = s_x * s_w;
        s_x_sh = s_x;
    }
    __syncthreads();
    float s_x = s_x_sh;
#pragma unroll
    for (int t = 0; t < 2; t++) {
        int j = tid + t * 1024;
        if (j < KK) qmul[j] = 1.0f / (sc_local[t] * s_x);
    }
}

// K-C: fused quantizers. Blocks 0..2047: im2col-quant of x. Blocks 2048..3199: quant_w.
#define QX_LDSROW 292
__global__ __launch_bounds__(256) void k_quant(const float* __restrict__ x,
                                               const float* __restrict__ wgt,
                                               const float* __restrict__ scale,
                                               const float* __restrict__ qmul,
                                               const float* __restrict__ scalars,
                                               signed char* __restrict__ qA,
                                               signed char* __restrict__ qW) {
    const int tid = threadIdx.x;
    if (blockIdx.x >= 2048) {
        int idx = (blockIdx.x - 2048) * 256 + tid;   // < 294912
        int j = idx % KK;
        float s_w = scalars[1];
        float t = wgt[idx] * scale[j];
        float q = rintf(t / s_w);
        q = fminf(fmaxf(q, -QMAXF), QMAXF);
        qW[idx] = (signed char)(int)q;
        return;
    }
    __shared__ float qm[288];                    // qmul slice [32 ch][9]
    __shared__ signed char ob[128 * QX_LDSROW];  // 128 px x 288(+4 pad) bytes
    const int qt  = blockIdx.x & 3;              // channel quarter
    const int rp  = (blockIdx.x >> 2) & 31;      // row pair
    const int b   = blockIdx.x >> 7;             // batch
    const int c0  = qt * 32;
    const int oh0 = rp * 2;

    for (int i = tid; i < 288; i += 256) qm[i] = qmul[c0 * 9 + i];
    __syncthreads();

    const int lane = tid & 63, wv = tid >> 6;
    const float* xb = x + (size_t)b * (C_IN * NPIX);

    for (int it = 0; it < 16; it++) {
        int pair = wv + 4 * it;          // 0..63 = (local c, row-in-pair)
        int c = pair >> 1;
        int oh = oh0 + (pair & 1);
        const float* xp = xb + (c0 + c) * NPIX + oh * 64 + lane;
        float xm = (oh >= 1)  ? xp[-64] : 0.f;
        float x0 = xp[0];
        float xq = (oh <= 62) ? xp[64]  : 0.f;
        float xm_l = __shfl_up(xm, 1);  if (lane == 0)  xm_l = 0.f;
        float xm_r = __shfl_down(xm, 1); if (lane == 63) xm_r = 0.f;
        float x0_l = __shfl_up(x0, 1);  if (lane == 0)  x0_l = 0.f;
        float x0_r = __shfl_down(x0, 1); if (lane == 63) x0_r = 0.f;
        float xq_l = __shfl_up(xq, 1);  if (lane == 0)  xq_l = 0.f;
        float xq_r = __shfl_down(xq, 1); if (lane == 63) xq_r = 0.f;
        float win[9] = { xm_l, xm, xm_r, x0_l, x0, x0_r, xq_l, xq, xq_r };
        signed char* orow = ob + ((oh - oh0) * 64 + lane) * QX_LDSROW + c * 9;
#pragma unroll
        for (int t = 0; t < 9; t++) {
            float q = rintf(win[t] * qm[c * 9 + t]);
            q = fminf(fmaxf(q, -QMAXF), QMAXF);
            orow[t] = (signed char)(int)q;
        }
    }
    __syncthreads();

    const int r0 = b * NPIX + oh0 * 64;
    for (int idx = tid; idx < 128 * 72; idx += 256) {
        int px = (unsigned)idx / 72u;
        int q  = idx - px * 72;
        int v  = *(const int*)(ob + px * QX_LDSROW + q * 4);
        *(int*)(qA + (size_t)(r0 + px) * KK + c0 * 9 + q * 4) = v;
    }
}

// K-D: int8 GEMM v3. Block tile 256(M-full) x 128(N), BK=128, 512 threads (8 waves,
// 4M x 2N). qA fetched exactly once device-wide. XOR-swizzled LDS (chunk p of row r
// holds global k-chunk p^(r&7)) -> fragment reads hit all 8 bank-groups (2-way = free).
__global__ __launch_bounds__(512) void k_gemm(const signed char* __restrict__ qW,
                                              const signed char* __restrict__ qA,
                                              const float* __restrict__ scalars,
                                              const float* __restrict__ bias,
                                              float* __restrict__ out) {
    __shared__ __align__(16) signed char As[256 * 128];  // 32 KB
    __shared__ __align__(16) signed char Bs[128 * 128];  // 16 KB
    const int tid = threadIdx.x;
    const int lane = tid & 63, wvid = tid >> 6;          // 8 waves
    const int wm = wvid & 3, wn = wvid >> 2;             // 4M x 2N
    const int blockN = blockIdx.x;                       // 0..511

    // staging: chunk = 8 rows x 128 B = 1 KB. lane: row r8=lane>>3, pos p=lane&7,
    // loads global k-chunk cp = p ^ r8  (swizzle key = row&7; chunks are 8-row aligned)
    const int r8 = lane >> 3;
    const int cp = (lane & 7) ^ r8;
    const int swz = lane & 7;            // un-swizzle key for fragment reads (row&7)

    v4i acc[4][4];
#pragma unroll
    for (int i = 0; i < 4; i++)
#pragma unroll
        for (int jq = 0; jq < 4; jq++) acc[i][jq] = (v4i){0, 0, 0, 0};

    for (int k0 = 0; k0 < KK; k0 += 128) {
        // 48 chunks total: 0..31 -> As (qW rows), 32..47 -> Bs (qA rows). 6 per wave.
#pragma unroll
        for (int i = 0; i < 6; i++) {
            int ch = wvid * 6 + i;
            const signed char* src;
            signed char* dst;
            if (ch < 32) {
                src = qW + (size_t)(ch * 8 + r8) * KK + k0 + cp * 16;
                dst = As + ch * 1024;
            } else {
                int cb = ch - 32;
                src = qA + ((size_t)blockN * 128 + cb * 8 + r8) * KK + k0 + cp * 16;
                dst = Bs + cb * 1024;
            }
            __builtin_amdgcn_global_load_lds(
                (const __attribute__((address_space(1))) void*)src,
                (__attribute__((address_space(3))) void*)dst, 16, 0, 0);
        }
        __syncthreads();
#pragma unroll
        for (int h = 0; h < 2; h++) {   // two K=64 sub-steps
            v4i af[4], bf[4];
            const int q4 = (h * 4 + (lane >> 4));
#pragma unroll
            for (int t = 0; t < 4; t++) {
                af[t] = *(const v4i*)(As + (wm * 64 + t * 16 + (lane & 15)) * 128 + (q4 ^ swz) * 16);
                bf[t] = *(const v4i*)(Bs + (wn * 64 + t * 16 + (lane & 15)) * 128 + (q4 ^ swz) * 16);
            }
#pragma unroll
            for (int mt = 0; mt < 4; mt++)
#pragma unroll
                for (int nt = 0; nt < 4; nt++)
                    acc[mt][nt] = __builtin_amdgcn_mfma_i32_16x16x64_i8(af[mt], bf[nt], acc[mt][nt], 0, 0, 0);
        }
        __syncthreads();
    }

    const float ssp = scalars[2];
    const int quad = lane >> 4, col = lane & 15;
    float bv[4][4];
#pragma unroll
    for (int mt = 0; mt < 4; mt++)
#pragma unroll
        for (int rg = 0; rg < 4; rg++)
            bv[mt][rg] = bias[wm * 64 + mt * 16 + quad * 4 + rg];

#pragma unroll
    for (int mt = 0; mt < 4; mt++) {
#pragma unroll
        for (int nt = 0; nt < 4; nt++) {
            int n_g = blockN * 128 + wn * 64 + nt * 16 + col;
            int b = n_g >> 12, pix = n_g & 4095;
#pragma unroll
            for (int rg = 0; rg < 4; rg++) {
                int m_g = wm * 64 + mt * 16 + quad * 4 + rg;
                float v = (float)acc[mt][nt][rg] * ssp + bv[mt][rg];
                out[(size_t)(b * C_OUT + m_g) * NPIX + pix] = v;
            }
        }
    }
}

extern "C" void kernel_launch(void* const* d_in, const int* in_sizes, int n_in,
                              void* d_out, int out_size, void* d_ws, size_t ws_size,
                              hipStream_t stream) {
    const float* x    = (const float*)d_in[0];
    const float* wgt  = (const float*)d_in[1];
    const float* bias = (const float*)d_in[2];
    float* out = (float*)d_out;

    char* ws = (char*)d_ws;
    signed char* qA = (signed char*)ws;
    signed char* qW = (signed char*)(ws + OFF_QW);
    float* w_part   = (float*)(ws + OFF_QW);      // aliases qW region (read before qW write)
    float* scale    = (float*)(ws + OFF_SCALE);
    float* qmul     = (float*)(ws + OFF_QMUL);
    float* act_part = (float*)(ws + OFF_APART);
    float* scalars  = (float*)(ws + OFF_SCAL);

    k_prep<<<1104, 256, 0, stream>>>(x, wgt, act_part, w_part);
    k_scales<<<1, 1024, 0, stream>>>(act_part, w_part, scale, qmul, scalars);
    k_quant<<<2048 + KK, 256, 0, stream>>>(x, wgt, scale, qmul, scalars, qA, qW);
    k_gemm<<<M_ROWS / 128, 512, 0, stream>>>(qW, qA, scalars, bias, out);
}

// Round 5
// 164.217 us; speedup vs baseline: 2.9990x; 1.0541x over previous
//
#include <hip/hip_runtime.h>
#include <cstdint>

// Problem constants
#define C_IN   128
#define C_OUT  256
#define KK     1152      // C_IN * 9 (im2col K)
#define NPIX   4096      // 64*64
#define BS     16
#define M_ROWS 65536     // BS * NPIX
#define QMAXF  127.0f

typedef int v4i __attribute__((ext_vector_type(4)));
typedef float f4 __attribute__((ext_vector_type(4)));

// ---- workspace layout (bytes) ----
// qW' (tap-major permuted) @ OFF_QW; w_part aliases it (read before qW' write).
#define OFF_QW    75497472
#define OFF_SCALE 75792384
#define OFF_QMUL  75796992
#define OFF_APART 75801600
#define OFF_SCAL  75843072

// K-A: fused act_scale (blocks 0..1023) + w_scale (blocks 1024..1103).
__global__ void k_prep(const float* __restrict__ x, const float* __restrict__ wgt,
                       float* __restrict__ act_part, float* __restrict__ w_part) {
    const int tid = threadIdx.x;
    if (blockIdx.x >= 1024) {
        int t = blockIdx.x - 1024;        // 0..79
        int j = (t % 5) * 256 + tid;
        int s = t / 5;                    // 0..15
        if (j >= KK) return;
        const float* p = wgt + (size_t)s * 16 * KK + j;
        float m = 0.f;
#pragma unroll
        for (int i = 0; i < 16; i++) m = fmaxf(m, fabsf(p[(size_t)i * KK]));
        w_part[s * KK + j] = m;
        return;
    }
    const int c = blockIdx.x >> 3, s = blockIdx.x & 7;
    float m[9];
#pragma unroll
    for (int i = 0; i < 9; i++) m[i] = 0.f;
    for (int p = tid; p < 2 * NPIX; p += 256) {
        int b = s * 2 + (p >> 12);
        int hw = p & 4095;
        int h = hw >> 6, w = hw & 63;
        float v = fabsf(x[b * (C_IN * NPIX) + c * NPIX + hw]);
        bool rr[3] = { h <= 62, true, h >= 1 };
        bool cc[3] = { w <= 62, true, w >= 1 };
#pragma unroll
        for (int i = 0; i < 3; i++)
#pragma unroll
            for (int jq = 0; jq < 3; jq++)
                m[i * 3 + jq] = fmaxf(m[i * 3 + jq], (rr[i] && cc[jq]) ? v : 0.f);
    }
    __shared__ float sm[9][4];
    int lane = tid & 63, wid = tid >> 6;
#pragma unroll
    for (int i = 0; i < 9; i++) {
        float v = m[i];
        for (int off = 32; off > 0; off >>= 1) v = fmaxf(v, __shfl_down(v, off));
        if (lane == 0) sm[i][wid] = v;
    }
    __syncthreads();
    if (tid < 9) {
        float v = fmaxf(fmaxf(sm[tid][0], sm[tid][1]), fmaxf(sm[tid][2], sm[tid][3]));
        act_part[s * KK + c * 9 + tid] = v;
    }
}

// K-B: scales + s_x + s_w + qmul. Single block, 1024 threads.
__global__ void k_scales(const float* __restrict__ act_part, const float* __restrict__ w_part,
                         float* __restrict__ scale, float* __restrict__ qmul,
                         float* __restrict__ scalars) {
    const int tid = threadIdx.x;
    float sc_local[2] = {1.f, 1.f};
    float mx = 0.f, mw = 0.f;
#pragma unroll
    for (int t = 0; t < 2; t++) {
        int j = tid + t * 1024;
        if (j < KK) {
            float a = 0.f;
#pragma unroll
            for (int s = 0; s < 8; s++) a = fmaxf(a, act_part[s * KK + j]);
            float wv = 0.f;
#pragma unroll
            for (int s = 0; s < 16; s++) wv = fmaxf(wv, w_part[s * KK + j]);
            float sc = sqrtf(a) / sqrtf(wv);
            if (sc == 0.f) sc = 1.0f;
            scale[j] = sc;
            sc_local[t] = sc;
            mx = fmaxf(mx, a / sc);    // exact: max_r |cols[r,j]/sc| == fl(act/sc)
            mw = fmaxf(mw, wv * sc);   // exact: max_i |w2[i,j]*sc|  == fl(wsc*sc)
        }
    }
    __shared__ float smx[16], smw[16];
    __shared__ float s_x_sh;
    int lane = tid & 63, wid = tid >> 6;
    for (int off = 32; off > 0; off >>= 1) {
        mx = fmaxf(mx, __shfl_down(mx, off));
        mw = fmaxf(mw, __shfl_down(mw, off));
    }
    if (lane == 0) { smx[wid] = mx; smw[wid] = mw; }
    __syncthreads();
    if (tid == 0) {
        float a = 0.f, b = 0.f;
        for (int i = 0; i < 16; i++) { a = fmaxf(a, smx[i]); b = fmaxf(b, smw[i]); }
        float s_x = a / QMAXF; if (s_x == 0.f) s_x = 1.f;
        float s_w = b / QMAXF; if (s_w == 0.f) s_w = 1.f;
        scalars[0] = s_x; scalars[1] = s_w; scalars[2] = s_x * s_w;
        s_x_sh = s_x;
    }
    __syncthreads();
    float s_x = s_x_sh;
#pragma unroll
    for (int t = 0; t < 2; t++) {
        int j = tid + t * 1024;
        if (j < KK) qmul[j] = 1.0f / (sc_local[t] * s_x);
    }
}

// K-C: quantize weights into TAP-MAJOR layout: qWp[m][tap*128 + c] = fq(w[m][c*9+tap]).
__global__ void k_quant_w(const float* __restrict__ wgt, const float* __restrict__ scale,
                          const float* __restrict__ scalars, signed char* __restrict__ qWp) {
    int idx = blockIdx.x * 256 + threadIdx.x;   // < 294912, coalesced WRITE
    int m  = (unsigned)idx / KK;
    int kp = idx - m * KK;
    int tap = kp >> 7, c = kp & 127;
    int j = c * 9 + tap;                        // original k index
    float s_w = scalars[1];
    float t = wgt[m * KK + j] * scale[j];
    float q = rintf(t / s_w);
    q = fminf(fmaxf(q, -QMAXF), QMAXF);
    qWp[idx] = (signed char)(int)q;
}

// K-D: FUSED quant+GEMM. Tap-major K: step `tap` = one (kh,kw) over all 128 channels.
// Block = 256(M) x 128(N=2 out rows of one image). 512 thr, 8 waves (4M x 2N).
// A: qWp staged via global_load_lds (XOR 16B-chunk swizzle, key=row&7).
// B: produced in-kernel — coalesced x row loads, quantize, ds_write_b128 (same swizzle).
__global__ __launch_bounds__(512) void k_gemm(const signed char* __restrict__ qWp,
                                              const float* __restrict__ x,
                                              const float* __restrict__ qmul,
                                              const float* __restrict__ scalars,
                                              const float* __restrict__ bias,
                                              float* __restrict__ out) {
    __shared__ __align__(16) signed char As[256 * 128];  // 32 KB
    __shared__ __align__(16) signed char Bs[128 * 128];  // 16 KB
    __shared__ float qm[KK];                             // permuted qmul [tap][c]
    const int tid = threadIdx.x;
    const int lane = tid & 63, wv = tid >> 6;
    const int wm = wv & 3, wn = wv >> 2;                 // 4M x 2N wave grid
    const int b   = blockIdx.x >> 5;
    const int rp  = blockIdx.x & 31;
    const int oh0 = rp * 2;
    const float* xb = x + (size_t)b * (C_IN * NPIX);

    for (int i = tid; i < KK; i += 512) {
        int tap = i >> 7, c = i & 127;
        qm[i] = qmul[c * 9 + tap];
    }

    // A-staging lane mapping: row-in-group r8, loads global chunk cp = p ^ r8
    const int r8 = lane >> 3;
    const int cpA = (lane & 7) ^ r8;
    // B-producer mapping
    const int ohl = wv & 1;              // local out row 0/1
    const int px  = ohl * 64 + lane;     // Bs row
    const int swz = lane & 7;            // = px & 7
    const int oh  = oh0 + ohl;

    v4i acc[4][4];
#pragma unroll
    for (int i = 0; i < 4; i++)
#pragma unroll
        for (int jq = 0; jq < 4; jq++) acc[i][jq] = (v4i){0, 0, 0, 0};

    __syncthreads();   // qm ready

    for (int tap = 0; tap < 9; tap++) {
        const int kh = (tap * 11) >> 5;          // tap/3 for 0..8
        const int kw = tap - kh * 3;
        const int ih = oh + kh - 1;              // wave-uniform
        const bool rowok = (unsigned)ih < 64u;
        // ---- A staging: 32 chunks of (8 rows x 128B), 4 per wave ----
#pragma unroll
        for (int i = 0; i < 4; i++) {
            int ch = wv * 4 + i;
            const signed char* src = qWp + (size_t)(ch * 8 + r8) * KK + tap * 128 + cpA * 16;
            __builtin_amdgcn_global_load_lds(
                (const __attribute__((address_space(1))) void*)src,
                (__attribute__((address_space(3))) void*)(As + ch * 1024), 16, 0, 0);
        }
        // ---- B producer: quantize x rows into Bs ----
        const int iw = lane + kw - 1;
        const bool colok = (unsigned)iw < 64u;
        const float* srow = xb + ih * 64 + iw;   // + c*NPIX per element
#pragma unroll
        for (int j = 0; j < 2; j++) {
            int cc = j * 4 + (wv >> 1);          // chunk 0..7
            int c0 = cc * 16;
            int pk[4];
#pragma unroll
            for (int d = 0; d < 4; d++) {
                f4 qv = *(const f4*)(qm + tap * 128 + c0 + d * 4);  // broadcast
                int w = 0;
#pragma unroll
                for (int e = 0; e < 4; e++) {
                    int c = c0 + d * 4 + e;
                    float v = (rowok && colok) ? srow[(size_t)c * NPIX] : 0.f;
                    float q = rintf(v * qv[e]);
                    q = fminf(fmaxf(q, -QMAXF), QMAXF);
                    w |= ((int)q & 255) << (8 * e);
                }
                pk[d] = w;
            }
            *(v4i*)(Bs + px * 128 + ((cc ^ swz) * 16)) = (v4i){pk[0], pk[1], pk[2], pk[3]};
        }
        __syncthreads();
        // ---- MFMA: BK=128 = two K=64 substeps ----
#pragma unroll
        for (int h = 0; h < 2; h++) {
            const int q4 = h * 4 + (lane >> 4);
            v4i af[4], bf[4];
#pragma unroll
            for (int t = 0; t < 4; t++) {
                int ra = wm * 64 + t * 16 + (lane & 15);
                af[t] = *(const v4i*)(As + ra * 128 + ((q4 ^ (ra & 7)) * 16));
                int rb = wn * 64 + t * 16 + (lane & 15);
                bf[t] = *(const v4i*)(Bs + rb * 128 + ((q4 ^ (rb & 7)) * 16));
            }
#pragma unroll
            for (int mt = 0; mt < 4; mt++)
#pragma unroll
                for (int nt = 0; nt < 4; nt++)
                    acc[mt][nt] = __builtin_amdgcn_mfma_i32_16x16x64_i8(af[mt], bf[nt], acc[mt][nt], 0, 0, 0);
        }
        __syncthreads();
    }

    const float ssp = scalars[2];
    const int quad = lane >> 4, col = lane & 15;
    float bv[4][4];
#pragma unroll
    for (int mt = 0; mt < 4; mt++)
#pragma unroll
        for (int rg = 0; rg < 4; rg++)
            bv[mt][rg] = bias[wm * 64 + mt * 16 + quad * 4 + rg];

#pragma unroll
    for (int mt = 0; mt < 4; mt++) {
#pragma unroll
        for (int nt = 0; nt < 4; nt++) {
            int n = wn * 64 + nt * 16 + col;                 // local pixel 0..127
#pragma unroll
            for (int rg = 0; rg < 4; rg++) {
                int m = wm * 64 + mt * 16 + quad * 4 + rg;   // c_out
                float v = (float)acc[mt][nt][rg] * ssp + bv[mt][rg];
                out[(size_t)(b * C_OUT + m) * NPIX + oh0 * 64 + n] = v;
            }
        }
    }
}

extern "C" void kernel_launch(void* const* d_in, const int* in_sizes, int n_in,
                              void* d_out, int out_size, void* d_ws, size_t ws_size,
                              hipStream_t stream) {
    const float* x    = (const float*)d_in[0];
    const float* wgt  = (const float*)d_in[1];
    const float* bias = (const float*)d_in[2];
    float* out = (float*)d_out;

    char* ws = (char*)d_ws;
    signed char* qWp = (signed char*)(ws + OFF_QW);
    float* w_part    = (float*)(ws + OFF_QW);     // aliases qWp (read before qWp write)
    float* scale     = (float*)(ws + OFF_SCALE);
    float* qmul      = (float*)(ws + OFF_QMUL);
    float* act_part  = (float*)(ws + OFF_APART);
    float* scalars   = (float*)(ws + OFF_SCAL);

    k_prep<<<1104, 256, 0, stream>>>(x, wgt, act_part, w_part);
    k_scales<<<1, 1024, 0, stream>>>(act_part, w_part, scale, qmul, scalars);
    k_quant_w<<<(C_OUT * KK) / 256, 256, 0, stream>>>(wgt, scale, scalars, qWp);
    k_gemm<<<BS * 32, 512, 0, stream>>>(qWp, x, qmul, scalars, bias, out);
}